// Round 2
// baseline (30.877 us; speedup 1.0000x reference)
//
#include <hip/hip_runtime.h>

#define D_IN  512
#define C_OUT 128
#define HW    16384   // 128*128 per batch
#define BM    128
#define BK    64
#define PAD   72      // BK + 8 bf16 elems -> 144B row stride, conflict-free b128 reads

typedef __attribute__((ext_vector_type(8))) short bf16x8;
typedef __attribute__((ext_vector_type(4))) float f32x4;

__device__ __forceinline__ ushort f2bf(float f) {
    uint32_t u = __builtin_bit_cast(uint32_t, f);
    uint32_t r = (u + 0x7fffu + ((u >> 16) & 1u)) >> 16;  // RNE
    return (ushort)r;
}

__global__ __launch_bounds__(256) void cwp_gemm(
    const float* __restrict__ x, const float* __restrict__ W,
    const float* __restrict__ bias, float* __restrict__ out)
{
    __shared__ ushort Ws[C_OUT * PAD];   // W tile  [c][k], bf16
    __shared__ ushort Xs[BM * PAD];      // x tile  [m][k], bf16

    const int t    = threadIdx.x;
    const int lane = t & 63;
    const int wid  = t >> 6;     // 0..3
    const int wr   = wid >> 1;   // c-half of block tile
    const int wc   = wid & 1;    // m-half of block tile
    const int q    = lane >> 4;  // 0..3
    const int lr   = lane & 15;

    const int m0   = blockIdx.x * BM;
    const int bidx = m0 / HW;
    const int hw0  = m0 % HW;

    f32x4 acc[4][4];
    #pragma unroll
    for (int i = 0; i < 4; ++i)
        #pragma unroll
        for (int j = 0; j < 4; ++j)
            acc[i][j] = (f32x4){0.f, 0.f, 0.f, 0.f};

    const int srow = t >> 4;  // 0..15: row-within-pass
    const int scol = t & 15;  // float4 column within BK

    for (int kt = 0; kt < D_IN; kt += BK) {
        // ---- load stage: 8 float4 of W + 8 float4 of x per thread ----
        float4 wv[8], xv[8];
        #pragma unroll
        for (int p = 0; p < 8; ++p) {
            const int r = p * 16 + srow;  // covers 128 rows
            wv[p] = *reinterpret_cast<const float4*>(&W[r * D_IN + kt + scol * 4]);
            xv[p] = *reinterpret_cast<const float4*>(&x[(size_t)(m0 + r) * D_IN + kt + scol * 4]);
        }
        __syncthreads();  // previous tile's compute done before LDS overwrite
        #pragma unroll
        for (int p = 0; p < 8; ++p) {
            const int r = p * 16 + srow;
            ushort4 wp = make_ushort4(f2bf(wv[p].x), f2bf(wv[p].y), f2bf(wv[p].z), f2bf(wv[p].w));
            ushort4 xp = make_ushort4(f2bf(xv[p].x), f2bf(xv[p].y), f2bf(xv[p].z), f2bf(xv[p].w));
            *reinterpret_cast<ushort4*>(&Ws[r * PAD + scol * 4]) = wp;
            *reinterpret_cast<ushort4*>(&Xs[r * PAD + scol * 4]) = xp;
        }
        __syncthreads();

        // ---- compute: 2 k-subs x 16 MFMA per wave ----
        #pragma unroll
        for (int ks = 0; ks < 2; ++ks) {
            bf16x8 af[4], bfv[4];
            #pragma unroll
            for (int i = 0; i < 4; ++i) {
                af[i]  = *reinterpret_cast<const bf16x8*>(&Ws[(wr*64 + i*16 + lr) * PAD + ks*32 + q*8]);
                bfv[i] = *reinterpret_cast<const bf16x8*>(&Xs[(wc*64 + i*16 + lr) * PAD + ks*32 + q*8]);
            }
            #pragma unroll
            for (int i = 0; i < 4; ++i)
                #pragma unroll
                for (int j = 0; j < 4; ++j)
                    acc[i][j] = __builtin_amdgcn_mfma_f32_16x16x32_bf16(af[i], bfv[j], acc[i][j], 0, 0, 0);
        }
    }

    // ---- epilogue: D[row=c-local][col=m-local]; row=(lane>>4)*4+jj, col=lane&15 ----
    float bv[4][4];
    #pragma unroll
    for (int i = 0; i < 4; ++i)
        #pragma unroll
        for (int jj = 0; jj < 4; ++jj)
            bv[i][jj] = bias[wr*64 + i*16 + q*4 + jj];

    float* outb = out + (size_t)bidx * C_OUT * HW;
    #pragma unroll
    for (int i = 0; i < 4; ++i) {
        const int c0 = wr*64 + i*16 + q*4;
        #pragma unroll
        for (int j = 0; j < 4; ++j) {
            const int m = hw0 + wc*64 + j*16 + lr;
            #pragma unroll
            for (int jj = 0; jj < 4; ++jj)
                outb[(size_t)(c0 + jj) * HW + m] = acc[i][j][jj] + bv[i][jj];
        }
    }
}

extern "C" void kernel_launch(void* const* d_in, const int* in_sizes, int n_in,
                              void* d_out, int out_size, void* d_ws, size_t ws_size,
                              hipStream_t stream) {
    const float* x    = (const float*)d_in[0];
    const float* W    = (const float*)d_in[1];
    const float* b    = (const float*)d_in[2];
    float* out        = (float*)d_out;
    const int M = 4 * HW;              // 65536 rows
    dim3 grid(M / BM);                 // 512 blocks
    cwp_gemm<<<grid, 256, 0, stream>>>(x, W, b, out);
}